// Round 4
// baseline (9.743 us; speedup 1.0000x reference)
//
#include <hip/hip_runtime.h>

__device__ __forceinline__ float2 mkc(float a, float b) { float2 r; r.x = a; r.y = b; return r; }
__device__ __forceinline__ float2 cmul(float2 a, float2 b) {
    return mkc(a.x * b.x - a.y * b.y, a.x * b.y + a.y * b.x);
}
__device__ __forceinline__ float2 cadd(float2 a, float2 b) { return mkc(a.x + b.x, a.y + b.y); }
__device__ __forceinline__ float2 muli(float2 a) { return mkc(-a.y, a.x); }       // * i
__device__ __forceinline__ float2 irot(float2 v, int m) {                          // * i^m
    m &= 3;
    if (m == 1) return mkc(-v.y, v.x);
    if (m == 2) return mkc(-v.x, -v.y);
    if (m == 3) return mkc(v.y, -v.x);
    return v;
}

struct cmat { float2 m[4]; };  // row-major [[m0 m1],[m2 m3]]

__device__ __forceinline__ cmat mmul(const cmat& A, const cmat& B) {
    cmat R;
    R.m[0] = cadd(cmul(A.m[0], B.m[0]), cmul(A.m[1], B.m[2]));
    R.m[1] = cadd(cmul(A.m[0], B.m[1]), cmul(A.m[1], B.m[3]));
    R.m[2] = cadd(cmul(A.m[2], B.m[0]), cmul(A.m[3], B.m[2]));
    R.m[3] = cadd(cmul(A.m[2], B.m[1]), cmul(A.m[3], B.m[3]));
    return R;
}
__device__ __forceinline__ cmat rxm(float t) {
    float c, s; __sincosf(0.5f * t, &s, &c);
    cmat R; R.m[0] = mkc(c, 0.f); R.m[1] = mkc(0.f, -s); R.m[2] = mkc(0.f, -s); R.m[3] = mkc(c, 0.f);
    return R;
}
__device__ __forceinline__ cmat rym(float t) {
    float c, s; __sincosf(0.5f * t, &s, &c);
    cmat R; R.m[0] = mkc(c, 0.f); R.m[1] = mkc(-s, 0.f); R.m[2] = mkc(s, 0.f); R.m[3] = mkc(c, 0.f);
    return R;
}

// column 0 of Rx(a2) @ Ry(a1) @ Rx(a0)   (layer-1 combined gate applied to |0>)
__device__ __forceinline__ void rxryrx_col0(float a0, float a1, float a2, float2& A, float2& B) {
    float s0, c0, s1, c1, s2, c2;
    __sincosf(0.5f * a0, &s0, &c0);
    __sincosf(0.5f * a1, &s1, &c1);
    __sincosf(0.5f * a2, &s2, &c2);
    float2 A1 = mkc(c1 * c0,  s1 * s0);
    float2 B1 = mkc(s1 * c0, -c1 * s0);
    A = mkc(c2 * A1.x + s2 * B1.y, c2 * A1.y - s2 * B1.x);
    B = mkc(c2 * B1.x + s2 * A1.y, c2 * B1.y - s2 * A1.x);
}

// ELEMS_PER_BLOCK waves per block, one batch element per wave, no barriers.
#define EPB 4

__global__ __launch_bounds__(EPB * 64) void qcnn_kernel(
    const float* __restrict__ x,        // (B,1,14,14)
    const float* __restrict__ conv_w,   // (1,1,4,4)
    const float* __restrict__ conv_b,   // (1,)
    const float* __restrict__ qw,       // (3,)
    float* __restrict__ out)            // (B,2)
{
    const int b = blockIdx.x * EPB + (threadIdx.x >> 6);
    const int t = threadIdx.x & 63;     // lane within wave

    // ---- conv (valid, stride 2, 4x4): lane t<36 computes angle t ----
    float ang = 0.f;
    if (t < 36) {
        int oy = t / 6, ox = t - oy * 6;
        const float* xb = x + b * 196 + oy * 28 + ox * 2;
        float acc = conv_b[0];
        #pragma unroll
        for (int ky = 0; ky < 4; ++ky)
            #pragma unroll
            for (int kx = 0; kx < 4; ++kx)
                acc += xb[ky * 14 + kx] * conv_w[ky * 4 + kx];
        ang = acc;
    }

    // ---- broadcast the angles needed wave-wide ----
    float a00 = __shfl(ang, 0),  a01 = __shfl(ang, 1),  a02 = __shfl(ang, 2);   // wire 0
    float a10 = __shfl(ang, 3),  a11 = __shfl(ang, 4),  a12 = __shfl(ang, 5);   // wire 1
    float aB0 = __shfl(ang, 33), aB1 = __shfl(ang, 34), aB2 = __shfl(ang, 35);  // wire 11

    // per-lane angles for wire w = t (used for wires 1..10)
    int base = (t < 12) ? ((t >> 1) * 6 + (t & 1) * 3) : 0;
    float g0 = __shfl(ang, base), g1 = __shfl(ang, base + 1), g2 = __shfl(ang, base + 2);

    // ---- per-wire probability terms for wires 1..10 (bits 0..9 after permutation) ----
    float2 termC = mkc(1.f, 0.f);   // q0 + i*q1  (for G(i))
    float  termR = 1.f;             // q0 - q1    (for G(-1))
    if (t >= 1 && t <= 10) {
        float2 A, B; rxryrx_col0(g0, g1, g2, A, B);
        float q0 = A.x * A.x + A.y * A.y;
        float q1 = B.x * B.x + B.y * B.y;
        termC = mkc(q0, q1);
        termR = q0 - q1;
    }
    // xor-butterfly product over lanes 0..15 (lanes 0,11..15 hold identity)
    #pragma unroll
    for (int m = 1; m < 16; m <<= 1) {
        float2 o = mkc(__shfl_xor(termC.x, m, 16), __shfl_xor(termC.y, m, 16));
        float  orr = __shfl_xor(termR, m, 16);
        termC = cmul(termC, o);
        termR *= orr;
    }
    float Gi_re = termC.x, Gi_im = termC.y, Gm = termR;

    // ---- small matrices, computed redundantly in every lane ----
    float2 v10_0, v10_1; rxryrx_col0(a00, a01, a02, v10_0, v10_1);  // wire 0  -> bit 10
    float2 v11_0, v11_1; rxryrx_col0(aB0, aB1, aB2, v11_0, v11_1);  // wire 11 -> bit 11
    cmat G11 = mmul(rym(a02), mmul(rxm(a01), rym(a00)));            // wire 0 layer-2 -> bit 11
    cmat G10 = mmul(rym(a12), mmul(rxm(a11), rym(a10)));            // wire 1 layer-2 -> bit 10
    cmat W   = mmul(rxm(qw[2]), mmul(rym(qw[1]), rxm(qw[0])));      // final, bit 11

    // ---- r = popcount bucket handled by this lane (lanes 0..3 meaningful) ----
    int r = t & 3;
    float sgn = (r & 1) ? -1.f : 1.f;
    float re2 = (r == 0) ?  2.f * Gi_re :
                (r == 1) ?  2.f * Gi_im :
                (r == 2) ? -2.f * Gi_re : -2.f * Gi_im;
    float Sr = 0.25f * (1.f + sgn * Gm + re2);

    float2 cr  = mkc((r == 0) ? 1.f : (r == 2) ? -1.f : 0.f,
                     (r == 1) ? 1.f : (r == 3) ? -1.f : 0.f);   // i^r
    float2 crc = mkc(cr.x, -cr.y);                              // i^-r

    // phi_r on (β10, β11); s index = (β11<<1)|β10
    float2 p00 = cmul(v10_0, v11_0);
    float2 p10 = cmul(v10_1, v11_0);
    float2 p01 = cmul(v10_0, v11_1);
    float2 p11 = cmul(v10_1, v11_1);
    float2 s0 = cmul(cr,  p00);              // i^(r)      * p00
    float2 s1 = cmul(cr,  muli(p10));        // i^(r+1)    * p10
    float2 s2 = cmul(crc, irot(p01, 3));     // i^(11-r)   * p01
    float2 s3 = cmul(crc, irot(p11, 2));     // i^(10-r)   * p11

    // G10 on β10: pairs (s0,s1),(s2,s3)
    {
        float2 n0 = cadd(cmul(G10.m[0], s0), cmul(G10.m[1], s1));
        float2 n1 = cadd(cmul(G10.m[2], s0), cmul(G10.m[3], s1));
        float2 n2 = cadd(cmul(G10.m[0], s2), cmul(G10.m[1], s3));
        float2 n3 = cadd(cmul(G10.m[2], s2), cmul(G10.m[3], s3));
        s0 = n0; s1 = n1; s2 = n2; s3 = n3;
    }
    // G11 on β11: pairs (s0,s2),(s1,s3)
    {
        float2 n0 = cadd(cmul(G11.m[0], s0), cmul(G11.m[1], s2));
        float2 n2 = cadd(cmul(G11.m[2], s0), cmul(G11.m[3], s2));
        float2 n1 = cadd(cmul(G11.m[0], s1), cmul(G11.m[1], s3));
        float2 n3 = cadd(cmul(G11.m[2], s1), cmul(G11.m[3], s3));
        s0 = n0; s1 = n1; s2 = n2; s3 = n3;
    }
    // iSWAP on bits (10,11): s1 <-> s2, each * i
    {
        float2 u = s1, v = s2;
        s1 = muli(v);
        s2 = muli(u);
    }
    // W on β11 fused with marginal:  T_r(j)
    float T0, T1;
    {
        float2 n00 = cadd(cmul(W.m[0], s0), cmul(W.m[1], s2));
        float2 n01 = cadd(cmul(W.m[0], s1), cmul(W.m[1], s3));
        float2 n10 = cadd(cmul(W.m[2], s0), cmul(W.m[3], s2));
        float2 n11 = cadd(cmul(W.m[2], s1), cmul(W.m[3], s3));
        T0 = n00.x * n00.x + n00.y * n00.y + n01.x * n01.x + n01.y * n01.y;
        T1 = n10.x * n10.x + n10.y * n10.y + n11.x * n11.x + n11.y * n11.y;
    }

    float p0 = Sr * T0, p1 = Sr * T1;
    // sum the 4 r-buckets (lanes 0..3)
    p0 += __shfl_xor(p0, 1, 4);  p0 += __shfl_xor(p0, 2, 4);
    p1 += __shfl_xor(p1, 1, 4);  p1 += __shfl_xor(p1, 2, 4);

    if (t == 0) {
        out[b * 2 + 0] = p0;
        out[b * 2 + 1] = p1;
    }
}

extern "C" void kernel_launch(void* const* d_in, const int* in_sizes, int n_in,
                              void* d_out, int out_size, void* d_ws, size_t ws_size,
                              hipStream_t stream) {
    const float* x      = (const float*)d_in[0];
    const float* conv_w = (const float*)d_in[1];
    const float* conv_b = (const float*)d_in[2];
    const float* qw     = (const float*)d_in[3];
    float* out          = (float*)d_out;

    int B = in_sizes[0] / 196;   // (B,1,14,14), B=256
    qcnn_kernel<<<dim3(B / EPB), dim3(EPB * 64), 0, stream>>>(x, conv_w, conv_b, qw, out);
}